// Round 9
// baseline (1815.446 us; speedup 1.0000x reference)
//
#include <hip/hip_runtime.h>

#define B 4096
#define T 2048
#define H 64
#define NBATCH 16
#define NB (B / NBATCH)     // 256 blocks -> 1 per CU
#define NTHREADS 512        // 8 waves -> 2 waves/SIMD, 2 cells/lane (dual-tile)

typedef __attribute__((ext_vector_type(8))) short short8;
typedef __attribute__((ext_vector_type(4))) float f32x4;
typedef __attribute__((ext_vector_type(2))) float f32x2;

__device__ __forceinline__ float ex2(float x) { return __builtin_amdgcn_exp2f(x); }
__device__ __forceinline__ unsigned short f2bf(float f) {  // RNE f32->bf16
    unsigned u = __builtin_bit_cast(unsigned, f);
    u += 0x7fffu + ((u >> 16) & 1u);
    return (unsigned short)(u >> 16);
}
// Pack two f32 -> two bf16 (RNE) in one instruction.
__device__ __forceinline__ unsigned pk_bf16(float a, float b) {
    unsigned r;
    asm("v_cvt_pk_bf16_f32 %0, %1, %2" : "=v"(r) : "v"(a), "v"(b));
    return r;
}
// Packed f32 (CDNA full-rate dual-FP32): 1 instr = 2 FLOPs/lane.
__device__ __forceinline__ f32x2 pk_mul(f32x2 a, f32x2 b) {
    f32x2 d; asm("v_pk_mul_f32 %0, %1, %2" : "=v"(d) : "v"(a), "v"(b)); return d;
}
__device__ __forceinline__ f32x2 pk_add(f32x2 a, f32x2 b) {
    f32x2 d; asm("v_pk_add_f32 %0, %1, %2" : "=v"(d) : "v"(a), "v"(b)); return d;
}
__device__ __forceinline__ f32x2 pk_fma(f32x2 a, f32x2 b, f32x2 c) {
    f32x2 d; asm("v_pk_fma_f32 %0, %1, %2, %3" : "=v"(d) : "v"(a), "v"(b), "v"(c)); return d;
}
__device__ __forceinline__ f32x2 pex2(f32x2 a) {   // elementwise 2^x
    float x, y;
    asm("v_exp_f32 %0, %1" : "=v"(x) : "v"(a.x));
    asm("v_exp_f32 %0, %1" : "=v"(y) : "v"(a.y));
    return (f32x2){x, y};
}
__device__ __forceinline__ f32x2 prcp(f32x2 a) {   // elementwise 1/x
    float x, y;
    asm("v_rcp_f32 %0, %1" : "=v"(x) : "v"(a.x));
    asm("v_rcp_f32 %0, %1" : "=v"(y) : "v"(a.y));
    return (f32x2){x, y};
}
// LDS-only barrier: drain lgkm (ds ops) but leave global loads in flight.
__device__ __forceinline__ void lds_barrier() {
    asm volatile("s_waitcnt lgkmcnt(0)\n\ts_barrier" ::: "memory");
}

// Packed dual-cell LSTM update. Inputs are the gate-interleaved MFMA quads:
//   z0 = {i_A, i_B, f_A, f_B},  z1 = {g_A, g_B, o_A, o_B}
// Exact math, single rcp for c':
//   c' = [c*(1+p0)(1+v) + (1-v)(1+pf)] / [(1+pf)(1+p0)(1+v)]
//   h  = (1-r) / ((1+s)(1+r)),  p*=2^(-1.4427*gate), v,r=2^(-2.8854*{g,cc})
__device__ __forceinline__ void cellstep2(const f32x4 z0, const f32x4 z1,
                                          f32x2& csp, f32x2& hsp, bool act) {
    const f32x2 ke2  = {-1.4426950408889634f, -1.4426950408889634f};
    const f32x2 kt2  = {-2.8853900817779268f, -2.8853900817779268f};
    const f32x2 one2 = {1.0f, 1.0f};
    const f32x2 mone2= {-1.0f, -1.0f};
    f32x2 pi = {z0[0], z0[1]}, pf = {z0[2], z0[3]};
    f32x2 pg = {z1[0], z1[1]}, po = {z1[2], z1[3]};
    f32x2 ei = pex2(pk_mul(pi, ke2));        // e^{-i}
    f32x2 ef = pex2(pk_mul(pf, ke2));        // e^{-f}
    f32x2 eg = pex2(pk_mul(pg, kt2));        // e^{-2g}
    f32x2 eo = pex2(pk_mul(po, ke2));        // e^{-o}
    f32x2 t1 = pk_add(ei, one2);             // 1+p0
    f32x2 t3 = pk_add(ef, one2);             // 1+pf
    f32x2 t2 = pk_add(eg, one2);             // 1+v
    f32x2 u  = pk_fma(eg, mone2, one2);      // 1-v
    f32x2 m1 = pk_mul(t1, t2);
    f32x2 D  = pk_mul(m1, t3);
    f32x2 rD = prcp(D);
    f32x2 N  = pk_fma(csp, m1, pk_mul(u, t3));
    f32x2 cn = pk_mul(N, rD);                // c'
    float ccx = fminf(15.f, fmaxf(-15.f, cn.x));
    float ccy = fminf(15.f, fmaxf(-15.f, cn.y));
    f32x2 er = pex2(pk_mul((f32x2){ccx, ccy}, kt2));  // e^{-2cc}
    f32x2 t5 = pk_add(er, one2);             // 1+r
    f32x2 w1 = pk_fma(er, mone2, one2);      // 1-r
    f32x2 t4 = pk_add(eo, one2);             // 1+s
    f32x2 hn = pk_mul(w1, prcp(pk_mul(t4, t5)));
    if (act) { csp = cn; hsp = hn; }
}

// ---------------------------------------------------------------------------
// Encoder: 256 blocks x 512 threads (8 waves, 2/SIMD), 16 batches, 2 cells/lane.
// GATE-INTERLEAVED tiles (r8-verified): tile 0 C = {i_A,i_B,f_A,f_B}, tile 1 =
// {g_A,g_B,o_A,o_B} for adjacent units uA=w*8+2hi, uB=uA+1.
// r9 change: K-halves accumulate into INDEPENDENT accumulators (z*a from hb0,
// z*b from hb1) summed after -- breaks the 2-deep MFMA dependency chain and
// decouples the hb1 read from hb0's MFMA on the recurrence critical path.
// ---------------------------------------------------------------------------
extern "C" __global__ void __launch_bounds__(NTHREADS, 2)
enc_kernel(const float* __restrict__ padded, const int* __restrict__ seq_len,
           const float* __restrict__ Wih, const float* __restrict__ Whh,
           const float* __restrict__ bias,
           float* __restrict__ h_out, float* __restrict__ c_out)
{
    __shared__ unsigned short hX[2][NBATCH][72];
    __shared__ int slen[NBATCH];

    const int tid = threadIdx.x;
    const int w = tid >> 6, L = tid & 63, lo = L & 15, hi = L >> 4;
    const int b0 = blockIdx.x * NBATCH;
    const int unitA = w * 8 + 2 * hi;      // even unit; uB = unitA+1

    // A-frags, gate-interleaved rows G(m,rt)
    short8 af[2][2];
    #pragma unroll
    for (int rt = 0; rt < 2; ++rt) {
        const int G = (rt * 2 + ((lo >> 1) & 1)) * 64 + w * 8 + 2 * (lo >> 2) + (lo & 1);
        #pragma unroll
        for (int kk = 0; kk < 2; ++kk) {
            const float* src = Whh + (long)G * H + kk * 32 + hi * 8;
            short8 f;
            #pragma unroll
            for (int j = 0; j < 8; ++j) f[j] = (short)f2bf(src[j]);
            af[rt][kk] = f;
        }
    }
    // z-init coefs: quad elem r of tile rt = gate (rt*2+(r>>1)), unit unitA+(r&1)
    float b_g[2][4], wi_g[2][4];
    #pragma unroll
    for (int rt = 0; rt < 2; ++rt)
        #pragma unroll
        for (int r = 0; r < 4; ++r) {
            const int G2 = (rt * 2 + (r >> 1)) * 64 + unitA + (r & 1);
            b_g[rt][r] = bias[G2];
            wi_g[rt][r] = Wih[G2];
        }

    for (int idx = tid; idx < NBATCH * 64; idx += NTHREADS)
        hX[0][idx >> 6][idx & 63] = 0;
    if (tid < NBATCH) slen[tid] = seq_len[b0 + tid];
    lds_barrier();

    int maxlen = 1;
    #pragma unroll
    for (int i = 0; i < NBATCH; ++i) maxlen = max(maxlen, slen[i]);
    const int len_lo = slen[lo];

    const float* xrow = padded + (long)(b0 + lo) * T;
    f32x4 xc = *(const f32x4*)(xrow);
    f32x4 xn = *(const f32x4*)(xrow + 4);

    f32x2 csp = {0.f, 0.f}, hsp = {0.f, 0.f};

#define ESTEP(P, XI)                                                          \
    {                                                                         \
        const float x = xc[XI];                                               \
        short8 hb0 = *(const short8*)&hX[P][lo][hi * 8];                      \
        short8 hb1 = *(const short8*)&hX[P][lo][32 + hi * 8];                 \
        f32x4 z0 = {b_g[0][0] + wi_g[0][0] * x, b_g[0][1] + wi_g[0][1] * x,   \
                    b_g[0][2] + wi_g[0][2] * x, b_g[0][3] + wi_g[0][3] * x};  \
        f32x4 z1 = {b_g[1][0] + wi_g[1][0] * x, b_g[1][1] + wi_g[1][1] * x,   \
                    b_g[1][2] + wi_g[1][2] * x, b_g[1][3] + wi_g[1][3] * x};  \
        f32x4 z0b = {0.f, 0.f, 0.f, 0.f}, z1b = {0.f, 0.f, 0.f, 0.f};         \
        z0  = __builtin_amdgcn_mfma_f32_16x16x32_bf16(af[0][0], hb0, z0,  0,0,0); \
        z1  = __builtin_amdgcn_mfma_f32_16x16x32_bf16(af[1][0], hb0, z1,  0,0,0); \
        z0b = __builtin_amdgcn_mfma_f32_16x16x32_bf16(af[0][1], hb1, z0b, 0,0,0); \
        z1b = __builtin_amdgcn_mfma_f32_16x16x32_bf16(af[1][1], hb1, z1b, 0,0,0); \
        z0 = z0 + z0b; z1 = z1 + z1b;                                         \
        const bool act = (t + XI) < len_lo;                                   \
        cellstep2(z0, z1, csp, hsp, act);                                     \
        *(unsigned*)&hX[(P) ^ 1][lo][unitA] = pk_bf16(hsp.x, hsp.y);          \
        lds_barrier();                                                        \
    }

    for (int t = 0; t < maxlen; t += 4) {
        int nb = t + 8; if (nb > T - 4) nb = T - 4;
        f32x4 xf = *(const f32x4*)(xrow + nb);   // 8-step-ahead prefetch
        ESTEP(0, 0) ESTEP(1, 1) ESTEP(0, 2) ESTEP(1, 3)
        xc = xn; xn = xf;
    }
#undef ESTEP

    *(f32x2*)&h_out[(long)(b0 + lo) * H + unitA] = hsp;
    *(f32x2*)&c_out[(long)(b0 + lo) * H + unitA] = csp;
}

// ---------------------------------------------------------------------------
// Bottleneck + y0 correction term for the decoder's rank-1 fold.
// ---------------------------------------------------------------------------
extern "C" __global__ void __launch_bounds__(256)
mid_kernel(const float* __restrict__ h_enc,
           const float* __restrict__ eW, const float* __restrict__ eb,
           const float* __restrict__ dW, const float* __restrict__ db,
           const float* __restrict__ outW, const float* __restrict__ outb,
           float* __restrict__ hz_out, float* __restrict__ hd_out,
           float* __restrict__ y0c)
{
    int b = blockIdx.x * blockDim.x + threadIdx.x;
    if (b >= B) return;
    const float* h = h_enc + (long)b * H;
    float hz[3];
    #pragma unroll
    for (int j = 0; j < 3; ++j) {
        float s = eb[j];
        for (int k = 0; k < H; ++k) s += h[k] * eW[j*H + k];
        hz[j] = 1.0f / (1.0f + __builtin_expf(-s));
        hz_out[b*3 + j] = hz[j];
    }
    float y0 = outb[0];
    for (int u = 0; u < H; ++u) {
        float hd = db[u] + hz[0]*dW[u*3] + hz[1]*dW[u*3+1] + hz[2]*dW[u*3+2];
        hd_out[(long)b*H + u] = hd;
        y0 += outW[u] * hd;
    }
    y0c[b] = y0;
}

// ---------------------------------------------------------------------------
// Decoder: rank-1 fold (W' = Whh + Wih (x) outW, b' = b + Wih*outb) -> pure
// LSTM. Same structure + split-accumulator MFMA. y_{t-1} via 2 extra MFMAs
// rotating across waves (w==t&7), one step delayed. t=0 corr peeled.
// ---------------------------------------------------------------------------
extern "C" __global__ void __launch_bounds__(NTHREADS, 2)
dec_kernel(const float* __restrict__ hd, const float* __restrict__ c_in,
           const float* __restrict__ Wih, const float* __restrict__ Whh,
           const float* __restrict__ bias, const float* __restrict__ outW,
           const float* __restrict__ outb, const float* __restrict__ y0c,
           float* __restrict__ y_out)
{
    __shared__ unsigned short hX[2][NBATCH][72];

    const int tid = threadIdx.x;
    const int w = tid >> 6, L = tid & 63, lo = L & 15, hi = L >> 4;
    const int b0 = blockIdx.x * NBATCH;
    const int unitA = w * 8 + 2 * hi;

    short8 af[2][2];
    #pragma unroll
    for (int rt = 0; rt < 2; ++rt) {
        const int G = (rt * 2 + ((lo >> 1) & 1)) * 64 + w * 8 + 2 * (lo >> 2) + (lo & 1);
        const float wir = Wih[G];
        #pragma unroll
        for (int kk = 0; kk < 2; ++kk) {
            const float* src = Whh + (long)G * H + kk * 32 + hi * 8;
            const float* ow  = outW + kk * 32 + hi * 8;
            short8 f;
            #pragma unroll
            for (int j = 0; j < 8; ++j) f[j] = (short)f2bf(src[j] + wir * ow[j]);
            af[rt][kk] = f;
        }
    }
    const float outb_s = outb[0];
    const float y0 = y0c[b0 + lo];
    float zb[2][4], corr[2][4];
    #pragma unroll
    for (int rt = 0; rt < 2; ++rt)
        #pragma unroll
        for (int r = 0; r < 4; ++r) {
            const int G2 = (rt * 2 + (r >> 1)) * 64 + unitA + (r & 1);
            zb[rt][r] = bias[G2] + Wih[G2] * outb_s;
            corr[rt][r] = Wih[G2] * y0;
        }

    short8 ya[2];   // y-extraction A-frag: row 0 = outW, rows 1..15 = 0
    #pragma unroll
    for (int kk = 0; kk < 2; ++kk) {
        short8 f = (short8)0;
        if (lo == 0)
            #pragma unroll
            for (int j = 0; j < 8; ++j) f[j] = (short)f2bf(outW[kk*32 + hi*8 + j]);
        ya[kk] = f;
    }

    for (int idx = tid; idx < NBATCH * 64; idx += NTHREADS)
        hX[0][idx >> 6][idx & 63] = f2bf(hd[(long)(b0 + (idx >> 6)) * H + (idx & 63)]);
    f32x2 csp = *(const f32x2*)&c_in[(long)(b0 + lo) * H + unitA];
    f32x2 hsp = {0.f, 0.f};
    lds_barrier();

#define DSTEP(P, CORR, TT)                                                    \
    {                                                                         \
        short8 hb0 = *(const short8*)&hX[P][lo][hi * 8];                      \
        short8 hb1 = *(const short8*)&hX[P][lo][32 + hi * 8];                 \
        f32x4 z0 = {zb[0][0], zb[0][1], zb[0][2], zb[0][3]};                  \
        f32x4 z1 = {zb[1][0], zb[1][1], zb[1][2], zb[1][3]};                  \
        f32x4 z0b = {0.f, 0.f, 0.f, 0.f}, z1b = {0.f, 0.f, 0.f, 0.f};         \
        z0  = __builtin_amdgcn_mfma_f32_16x16x32_bf16(af[0][0], hb0, z0,  0,0,0); \
        z1  = __builtin_amdgcn_mfma_f32_16x16x32_bf16(af[1][0], hb0, z1,  0,0,0); \
        z0b = __builtin_amdgcn_mfma_f32_16x16x32_bf16(af[0][1], hb1, z0b, 0,0,0); \
        z1b = __builtin_amdgcn_mfma_f32_16x16x32_bf16(af[1][1], hb1, z1b, 0,0,0); \
        z0 = z0 + z0b; z1 = z1 + z1b;                                         \
        if (w == ((TT) & 7)) {  /* y_{t-1} = outW.h_{t-1}+outb, rotated */    \
            f32x4 zy = {outb_s, outb_s, outb_s, outb_s};                      \
            zy = __builtin_amdgcn_mfma_f32_16x16x32_bf16(ya[0], hb0, zy, 0,0,0); \
            zy = __builtin_amdgcn_mfma_f32_16x16x32_bf16(ya[1], hb1, zy, 0,0,0); \
            if ((TT) > 0 && hi == 0)                                          \
                y_out[(long)(b0 + lo) * T + ((TT) - 1)] = zy[0];              \
        }                                                                     \
        if (CORR) {                                                           \
            _Pragma("unroll")                                                 \
            for (int r = 0; r < 4; ++r) { z0[r] -= corr[0][r]; z1[r] -= corr[1][r]; } \
        }                                                                     \
        cellstep2(z0, z1, csp, hsp, true);                                    \
        *(unsigned*)&hX[(P) ^ 1][lo][unitA] = pk_bf16(hsp.x, hsp.y);          \
        lds_barrier();                                                        \
    }

    DSTEP(0, 1, 0) DSTEP(1, 0, 1) DSTEP(0, 0, 2) DSTEP(1, 0, 3)
    for (int t = 4; t < T; t += 4) {
        DSTEP(0, 0, t) DSTEP(1, 0, t + 1) DSTEP(0, 0, t + 2) DSTEP(1, 0, t + 3)
    }
#undef DSTEP

    if (w == 0) {       // final y_{T-1} (T even -> parity 0)
        short8 hb0 = *(const short8*)&hX[0][lo][hi * 8];
        short8 hb1 = *(const short8*)&hX[0][lo][32 + hi * 8];
        f32x4 zy = {outb_s, outb_s, outb_s, outb_s};
        zy = __builtin_amdgcn_mfma_f32_16x16x32_bf16(ya[0], hb0, zy, 0,0,0);
        zy = __builtin_amdgcn_mfma_f32_16x16x32_bf16(ya[1], hb1, zy, 0,0,0);
        if (hi == 0) y_out[(long)(b0 + lo) * T + (T - 1)] = zy[0];
    }
}

// ---------------------------------------------------------------------------
extern "C" __global__ void __launch_bounds__(256)
loss_kernel(const float* __restrict__ padded, const float* __restrict__ y,
            const int* __restrict__ seq_len, float* __restrict__ acc2)
{
    const long n4 = (long)B * T / 4;
    long i0 = (long)(blockIdx.x * blockDim.x + threadIdx.x);
    long stride = (long)gridDim.x * blockDim.x;
    float s = 0.f, cnt = 0.f;
    for (long i = i0; i < n4; i += stride) {
        int b = (int)(i >> 9);                  // T/4 = 512
        int t = (int)(i & 511) * 4;
        int len = seq_len[b];
        f32x4 pv = *(const f32x4*)&padded[i * 4];
        f32x4 yv = *(const f32x4*)&y[i * 4];
        #pragma unroll
        for (int e = 0; e < 4; ++e)
            if (t + e < len) { float d = pv[e] - yv[e]; s += d * d; cnt += 1.0f; }
    }
    for (int m = 1; m < 64; m <<= 1) { s += __shfl_xor(s, m); cnt += __shfl_xor(cnt, m); }
    if ((threadIdx.x & 63) == 0) { atomicAdd(&acc2[0], s); atomicAdd(&acc2[1], cnt); }
}

extern "C" __global__ void fin_kernel(const float* __restrict__ acc2, float* __restrict__ out)
{
    out[0] = acc2[0] / acc2[1];
}

// ---------------------------------------------------------------------------
extern "C" void kernel_launch(void* const* d_in, const int* in_sizes, int n_in,
                              void* d_out, int out_size, void* d_ws, size_t ws_size,
                              hipStream_t stream)
{
    const float* padded = (const float*)d_in[0];
    const int*   seq    = (const int*)  d_in[1];
    const float* eWih   = (const float*)d_in[2];
    const float* eWhh   = (const float*)d_in[3];
    const float* eb     = (const float*)d_in[4];
    const float* elW    = (const float*)d_in[5];
    const float* elb    = (const float*)d_in[6];
    const float* dlW    = (const float*)d_in[7];
    const float* dlb    = (const float*)d_in[8];
    const float* dWih   = (const float*)d_in[9];
    const float* dWhh   = (const float*)d_in[10];
    const float* db     = (const float*)d_in[11];
    const float* outW   = (const float*)d_in[12];
    const float* outb   = (const float*)d_in[13];
    float* out = (float*)d_out;

    float* ws    = (float*)d_ws;
    float* h_enc = ws;
    float* c_enc = ws + (long)B * H;
    float* hd    = ws + 2L * B * H;
    float* y0c   = ws + 3L * B * H;
    float* acc2  = ws + 3L * B * H + B;

    float* out_pad = out + 1;
    float* out_y   = out + 1 + (long)B * T;
    float* out_hz  = out + 1 + 2L * (long)B * T;

    hipMemcpyAsync(out_pad, padded, (long)B * T * sizeof(float),
                   hipMemcpyDeviceToDevice, stream);
    hipMemsetAsync(acc2, 0, 2 * sizeof(float), stream);

    enc_kernel<<<NB, NTHREADS, 0, stream>>>(padded, seq, eWih, eWhh, eb, h_enc, c_enc);
    mid_kernel<<<B / 256, 256, 0, stream>>>(h_enc, elW, elb, dlW, dlb, outW, outb,
                                            out_hz, hd, y0c);
    dec_kernel<<<NB, NTHREADS, 0, stream>>>(hd, c_enc, dWih, dWhh, db, outW, outb, y0c, out_y);
    loss_kernel<<<1024, 256, 0, stream>>>(padded, out_y, seq, acc2);
    fin_kernel<<<1, 1, 0, stream>>>(acc2, out);
}

// Round 10
// 1757.699 us; speedup vs baseline: 1.0329x; 1.0329x over previous
//
#include <hip/hip_runtime.h>

#define B 4096
#define T 2048
#define H 64
#define NBATCH 16
#define NB (B / NBATCH)     // 256 blocks -> 1 per CU
#define NTHREADS 512        // 8 waves -> 2 waves/SIMD, 2 cells/lane (dual-tile)

typedef __attribute__((ext_vector_type(8))) short short8;
typedef __attribute__((ext_vector_type(4))) float f32x4;
typedef __attribute__((ext_vector_type(2))) float f32x2;

__device__ __forceinline__ float ex2(float x) { return __builtin_amdgcn_exp2f(x); }
__device__ __forceinline__ unsigned short f2bf(float f) {  // RNE f32->bf16
    unsigned u = __builtin_bit_cast(unsigned, f);
    u += 0x7fffu + ((u >> 16) & 1u);
    return (unsigned short)(u >> 16);
}
// Pack two f32 -> two bf16 (RNE) in one instruction.
__device__ __forceinline__ unsigned pk_bf16(float a, float b) {
    unsigned r;
    asm("v_cvt_pk_bf16_f32 %0, %1, %2" : "=v"(r) : "v"(a), "v"(b));
    return r;
}
// Packed f32 (CDNA full-rate dual-FP32): 1 instr = 2 FLOPs/lane.
__device__ __forceinline__ f32x2 pk_mul(f32x2 a, f32x2 b) {
    f32x2 d; asm("v_pk_mul_f32 %0, %1, %2" : "=v"(d) : "v"(a), "v"(b)); return d;
}
__device__ __forceinline__ f32x2 pk_add(f32x2 a, f32x2 b) {
    f32x2 d; asm("v_pk_add_f32 %0, %1, %2" : "=v"(d) : "v"(a), "v"(b)); return d;
}
__device__ __forceinline__ f32x2 pk_fma(f32x2 a, f32x2 b, f32x2 c) {
    f32x2 d; asm("v_pk_fma_f32 %0, %1, %2, %3" : "=v"(d) : "v"(a), "v"(b), "v"(c)); return d;
}
__device__ __forceinline__ f32x2 pex2(f32x2 a) {   // elementwise 2^x
    float x, y;
    asm("v_exp_f32 %0, %1" : "=v"(x) : "v"(a.x));
    asm("v_exp_f32 %0, %1" : "=v"(y) : "v"(a.y));
    return (f32x2){x, y};
}
__device__ __forceinline__ f32x2 prcp(f32x2 a) {   // elementwise 1/x
    float x, y;
    asm("v_rcp_f32 %0, %1" : "=v"(x) : "v"(a.x));
    asm("v_rcp_f32 %0, %1" : "=v"(y) : "v"(a.y));
    return (f32x2){x, y};
}
__device__ __forceinline__ float med3(float x, float lo, float hi) {  // clamp
    float d; asm("v_med3_f32 %0, %1, %2, %3" : "=v"(d) : "v"(x), "v"(lo), "v"(hi));
    return d;
}
// LDS-only barrier: drain lgkm (ds ops) but leave global loads in flight.
__device__ __forceinline__ void lds_barrier() {
    asm volatile("s_waitcnt lgkmcnt(0)\n\ts_barrier" ::: "memory");
}

// Packed dual-cell LSTM update. Inputs are the gate-interleaved MFMA quads:
//   z0 = {i_A, i_B, f_A, f_B},  z1 = {g_A, g_B, o_A, o_B}
// Exact math, single rcp for c':
//   c' = [c*(1+p0)(1+v) + (1-v)(1+pf)] / [(1+pf)(1+p0)(1+v)]
//   h  = (1-r) / ((1+s)(1+r)),  p*=2^(-1.4427*gate), v,r=2^(-2.8854*{g,cc})
__device__ __forceinline__ void cellstep2(const f32x4 z0, const f32x4 z1,
                                          f32x2& csp, f32x2& hsp, bool act) {
    const f32x2 ke2  = {-1.4426950408889634f, -1.4426950408889634f};
    const f32x2 kt2  = {-2.8853900817779268f, -2.8853900817779268f};
    const f32x2 one2 = {1.0f, 1.0f};
    const f32x2 mone2= {-1.0f, -1.0f};
    f32x2 pi = {z0[0], z0[1]}, pf = {z0[2], z0[3]};
    f32x2 pg = {z1[0], z1[1]}, po = {z1[2], z1[3]};
    f32x2 ei = pex2(pk_mul(pi, ke2));        // e^{-i}
    f32x2 ef = pex2(pk_mul(pf, ke2));        // e^{-f}
    f32x2 eg = pex2(pk_mul(pg, kt2));        // e^{-2g}
    f32x2 eo = pex2(pk_mul(po, ke2));        // e^{-o}
    f32x2 t1 = pk_add(ei, one2);             // 1+p0
    f32x2 t3 = pk_add(ef, one2);             // 1+pf
    f32x2 t2 = pk_add(eg, one2);             // 1+v
    f32x2 u  = pk_fma(eg, mone2, one2);      // 1-v
    f32x2 m1 = pk_mul(t1, t2);
    f32x2 D  = pk_mul(m1, t3);
    f32x2 rD = prcp(D);
    f32x2 N  = pk_fma(csp, m1, pk_mul(u, t3));
    f32x2 cn = pk_mul(N, rD);                // c'
    float ccx = med3(cn.x, -15.f, 15.f);
    float ccy = med3(cn.y, -15.f, 15.f);
    f32x2 er = pex2(pk_mul((f32x2){ccx, ccy}, kt2));  // e^{-2cc}
    f32x2 t5 = pk_add(er, one2);             // 1+r
    f32x2 w1 = pk_fma(er, mone2, one2);      // 1-r
    f32x2 t4 = pk_add(eo, one2);             // 1+s
    f32x2 hn = pk_mul(w1, prcp(pk_mul(t4, t5)));
    if (act) { csp = cn; hsp = hn; }
}

// ---------------------------------------------------------------------------
// Encoder: 256 blocks x 512 threads (8 waves, 2/SIMD), 16 batches, 2 cells/lane.
// GATE-INTERLEAVED tiles (r8-verified): tile 0 C = {i_A,i_B,f_A,f_B}, tile 1 =
// {g_A,g_B,o_A,o_B} for adjacent units uA=w*8+2hi, uB=uA+1. Chained K-half
// MFMA accumulate (r9 showed chaining is near-free; split-acc regressed).
// z-init via pk_fma on pre-paired (b,wi) coefficients.
// ---------------------------------------------------------------------------
extern "C" __global__ void __launch_bounds__(NTHREADS, 2)
enc_kernel(const float* __restrict__ padded, const int* __restrict__ seq_len,
           const float* __restrict__ Wih, const float* __restrict__ Whh,
           const float* __restrict__ bias,
           float* __restrict__ h_out, float* __restrict__ c_out)
{
    __shared__ unsigned short hX[2][NBATCH][72];
    __shared__ int slen[NBATCH];

    const int tid = threadIdx.x;
    const int w = tid >> 6, L = tid & 63, lo = L & 15, hi = L >> 4;
    const int b0 = blockIdx.x * NBATCH;
    const int unitA = w * 8 + 2 * hi;      // even unit; uB = unitA+1

    // A-frags, gate-interleaved rows G(m,rt)
    short8 af[2][2];
    #pragma unroll
    for (int rt = 0; rt < 2; ++rt) {
        const int G = (rt * 2 + ((lo >> 1) & 1)) * 64 + w * 8 + 2 * (lo >> 2) + (lo & 1);
        #pragma unroll
        for (int kk = 0; kk < 2; ++kk) {
            const float* src = Whh + (long)G * H + kk * 32 + hi * 8;
            short8 f;
            #pragma unroll
            for (int j = 0; j < 8; ++j) f[j] = (short)f2bf(src[j]);
            af[rt][kk] = f;
        }
    }
    // z-init coefs as packed pairs: quad elems (2p, 2p+1) of tile rt
    f32x2 bg2[2][2], wg2[2][2];
    #pragma unroll
    for (int rt = 0; rt < 2; ++rt)
        #pragma unroll
        for (int p = 0; p < 2; ++p) {
            // elem r = 2p+e : gate (rt*2+p), unit unitA+e
            const int Gb = (rt * 2 + p) * 64 + unitA;
            bg2[rt][p] = (f32x2){bias[Gb], bias[Gb + 1]};
            wg2[rt][p] = (f32x2){Wih[Gb], Wih[Gb + 1]};
        }

    for (int idx = tid; idx < NBATCH * 64; idx += NTHREADS)
        hX[0][idx >> 6][idx & 63] = 0;
    if (tid < NBATCH) slen[tid] = seq_len[b0 + tid];
    lds_barrier();

    int maxlen = 1;
    #pragma unroll
    for (int i = 0; i < NBATCH; ++i) maxlen = max(maxlen, slen[i]);
    const int len_lo = slen[lo];

    const float* xrow = padded + (long)(b0 + lo) * T;
    f32x4 xc = *(const f32x4*)(xrow);
    f32x4 xn = *(const f32x4*)(xrow + 4);

    f32x2 csp = {0.f, 0.f}, hsp = {0.f, 0.f};

#define ESTEP(P, XI)                                                          \
    {                                                                         \
        const f32x2 xx = {xc[XI], xc[XI]};                                    \
        short8 hb0 = *(const short8*)&hX[P][lo][hi * 8];                      \
        short8 hb1 = *(const short8*)&hX[P][lo][32 + hi * 8];                 \
        f32x2 p00 = pk_fma(wg2[0][0], xx, bg2[0][0]);                         \
        f32x2 p01 = pk_fma(wg2[0][1], xx, bg2[0][1]);                         \
        f32x2 p10 = pk_fma(wg2[1][0], xx, bg2[1][0]);                         \
        f32x2 p11 = pk_fma(wg2[1][1], xx, bg2[1][1]);                         \
        f32x4 z0 = {p00.x, p00.y, p01.x, p01.y};                              \
        f32x4 z1 = {p10.x, p10.y, p11.x, p11.y};                              \
        z0 = __builtin_amdgcn_mfma_f32_16x16x32_bf16(af[0][0], hb0, z0, 0,0,0); \
        z1 = __builtin_amdgcn_mfma_f32_16x16x32_bf16(af[1][0], hb0, z1, 0,0,0); \
        z0 = __builtin_amdgcn_mfma_f32_16x16x32_bf16(af[0][1], hb1, z0, 0,0,0); \
        z1 = __builtin_amdgcn_mfma_f32_16x16x32_bf16(af[1][1], hb1, z1, 0,0,0); \
        const bool act = (t + XI) < len_lo;                                   \
        cellstep2(z0, z1, csp, hsp, act);                                     \
        *(unsigned*)&hX[(P) ^ 1][lo][unitA] = pk_bf16(hsp.x, hsp.y);          \
        lds_barrier();                                                        \
    }

    for (int t = 0; t < maxlen; t += 4) {
        int nb = t + 8; if (nb > T - 4) nb = T - 4;
        f32x4 xf = *(const f32x4*)(xrow + nb);   // 8-step-ahead prefetch
        ESTEP(0, 0) ESTEP(1, 1) ESTEP(0, 2) ESTEP(1, 3)
        xc = xn; xn = xf;
    }
#undef ESTEP

    *(f32x2*)&h_out[(long)(b0 + lo) * H + unitA] = hsp;
    *(f32x2*)&c_out[(long)(b0 + lo) * H + unitA] = csp;
}

// ---------------------------------------------------------------------------
// Bottleneck + y0 correction term for the decoder's rank-1 fold.
// ---------------------------------------------------------------------------
extern "C" __global__ void __launch_bounds__(256)
mid_kernel(const float* __restrict__ h_enc,
           const float* __restrict__ eW, const float* __restrict__ eb,
           const float* __restrict__ dW, const float* __restrict__ db,
           const float* __restrict__ outW, const float* __restrict__ outb,
           float* __restrict__ hz_out, float* __restrict__ hd_out,
           float* __restrict__ y0c)
{
    int b = blockIdx.x * blockDim.x + threadIdx.x;
    if (b >= B) return;
    const float* h = h_enc + (long)b * H;
    float hz[3];
    #pragma unroll
    for (int j = 0; j < 3; ++j) {
        float s = eb[j];
        for (int k = 0; k < H; ++k) s += h[k] * eW[j*H + k];
        hz[j] = 1.0f / (1.0f + __builtin_expf(-s));
        hz_out[b*3 + j] = hz[j];
    }
    float y0 = outb[0];
    for (int u = 0; u < H; ++u) {
        float hd = db[u] + hz[0]*dW[u*3] + hz[1]*dW[u*3+1] + hz[2]*dW[u*3+2];
        hd_out[(long)b*H + u] = hd;
        y0 += outW[u] * hd;
    }
    y0c[b] = y0;
}

// ---------------------------------------------------------------------------
// Decoder: rank-1 fold (W' = Whh + Wih (x) outW, b' = b + Wih*outb) -> pure
// LSTM. Same structure + gate-interleaved packed act. y_{t-1} via 2 extra
// MFMAs rotating across waves (w==t&7), one step delayed. t=0 corr peeled.
// ---------------------------------------------------------------------------
extern "C" __global__ void __launch_bounds__(NTHREADS, 2)
dec_kernel(const float* __restrict__ hd, const float* __restrict__ c_in,
           const float* __restrict__ Wih, const float* __restrict__ Whh,
           const float* __restrict__ bias, const float* __restrict__ outW,
           const float* __restrict__ outb, const float* __restrict__ y0c,
           float* __restrict__ y_out)
{
    __shared__ unsigned short hX[2][NBATCH][72];

    const int tid = threadIdx.x;
    const int w = tid >> 6, L = tid & 63, lo = L & 15, hi = L >> 4;
    const int b0 = blockIdx.x * NBATCH;
    const int unitA = w * 8 + 2 * hi;

    short8 af[2][2];
    #pragma unroll
    for (int rt = 0; rt < 2; ++rt) {
        const int G = (rt * 2 + ((lo >> 1) & 1)) * 64 + w * 8 + 2 * (lo >> 2) + (lo & 1);
        const float wir = Wih[G];
        #pragma unroll
        for (int kk = 0; kk < 2; ++kk) {
            const float* src = Whh + (long)G * H + kk * 32 + hi * 8;
            const float* ow  = outW + kk * 32 + hi * 8;
            short8 f;
            #pragma unroll
            for (int j = 0; j < 8; ++j) f[j] = (short)f2bf(src[j] + wir * ow[j]);
            af[rt][kk] = f;
        }
    }
    const float outb_s = outb[0];
    const float y0 = y0c[b0 + lo];
    float zb[2][4], corr[2][4];
    #pragma unroll
    for (int rt = 0; rt < 2; ++rt)
        #pragma unroll
        for (int r = 0; r < 4; ++r) {
            const int G2 = (rt * 2 + (r >> 1)) * 64 + unitA + (r & 1);
            zb[rt][r] = bias[G2] + Wih[G2] * outb_s;
            corr[rt][r] = Wih[G2] * y0;
        }

    short8 ya[2];   // y-extraction A-frag: row 0 = outW, rows 1..15 = 0
    #pragma unroll
    for (int kk = 0; kk < 2; ++kk) {
        short8 f = (short8)0;
        if (lo == 0)
            #pragma unroll
            for (int j = 0; j < 8; ++j) f[j] = (short)f2bf(outW[kk*32 + hi*8 + j]);
        ya[kk] = f;
    }

    for (int idx = tid; idx < NBATCH * 64; idx += NTHREADS)
        hX[0][idx >> 6][idx & 63] = f2bf(hd[(long)(b0 + (idx >> 6)) * H + (idx & 63)]);
    f32x2 csp = *(const f32x2*)&c_in[(long)(b0 + lo) * H + unitA];
    f32x2 hsp = {0.f, 0.f};
    lds_barrier();

#define DSTEP(P, CORR, TT)                                                    \
    {                                                                         \
        short8 hb0 = *(const short8*)&hX[P][lo][hi * 8];                      \
        short8 hb1 = *(const short8*)&hX[P][lo][32 + hi * 8];                 \
        f32x4 z0 = {zb[0][0], zb[0][1], zb[0][2], zb[0][3]};                  \
        f32x4 z1 = {zb[1][0], zb[1][1], zb[1][2], zb[1][3]};                  \
        z0 = __builtin_amdgcn_mfma_f32_16x16x32_bf16(af[0][0], hb0, z0, 0,0,0); \
        z1 = __builtin_amdgcn_mfma_f32_16x16x32_bf16(af[1][0], hb0, z1, 0,0,0); \
        z0 = __builtin_amdgcn_mfma_f32_16x16x32_bf16(af[0][1], hb1, z0, 0,0,0); \
        z1 = __builtin_amdgcn_mfma_f32_16x16x32_bf16(af[1][1], hb1, z1, 0,0,0); \
        if (w == ((TT) & 7)) {  /* y_{t-1} = outW.h_{t-1}+outb, rotated */    \
            f32x4 zy = {outb_s, outb_s, outb_s, outb_s};                      \
            zy = __builtin_amdgcn_mfma_f32_16x16x32_bf16(ya[0], hb0, zy, 0,0,0); \
            zy = __builtin_amdgcn_mfma_f32_16x16x32_bf16(ya[1], hb1, zy, 0,0,0); \
            if ((TT) > 0 && hi == 0)                                          \
                y_out[(long)(b0 + lo) * T + ((TT) - 1)] = zy[0];              \
        }                                                                     \
        if (CORR) {                                                           \
            _Pragma("unroll")                                                 \
            for (int r = 0; r < 4; ++r) { z0[r] -= corr[0][r]; z1[r] -= corr[1][r]; } \
        }                                                                     \
        cellstep2(z0, z1, csp, hsp, true);                                    \
        *(unsigned*)&hX[(P) ^ 1][lo][unitA] = pk_bf16(hsp.x, hsp.y);          \
        lds_barrier();                                                        \
    }

    DSTEP(0, 1, 0) DSTEP(1, 0, 1) DSTEP(0, 0, 2) DSTEP(1, 0, 3)
    for (int t = 4; t < T; t += 4) {
        DSTEP(0, 0, t) DSTEP(1, 0, t + 1) DSTEP(0, 0, t + 2) DSTEP(1, 0, t + 3)
    }
#undef DSTEP

    if (w == 0) {       // final y_{T-1} (T even -> parity 0)
        short8 hb0 = *(const short8*)&hX[0][lo][hi * 8];
        short8 hb1 = *(const short8*)&hX[0][lo][32 + hi * 8];
        f32x4 zy = {outb_s, outb_s, outb_s, outb_s};
        zy = __builtin_amdgcn_mfma_f32_16x16x32_bf16(ya[0], hb0, zy, 0,0,0);
        zy = __builtin_amdgcn_mfma_f32_16x16x32_bf16(ya[1], hb1, zy, 0,0,0);
        if (hi == 0) y_out[(long)(b0 + lo) * T + (T - 1)] = zy[0];
    }
}

// ---------------------------------------------------------------------------
extern "C" __global__ void __launch_bounds__(256)
loss_kernel(const float* __restrict__ padded, const float* __restrict__ y,
            const int* __restrict__ seq_len, float* __restrict__ acc2)
{
    const long n4 = (long)B * T / 4;
    long i0 = (long)(blockIdx.x * blockDim.x + threadIdx.x);
    long stride = (long)gridDim.x * blockDim.x;
    float s = 0.f, cnt = 0.f;
    for (long i = i0; i < n4; i += stride) {
        int b = (int)(i >> 9);                  // T/4 = 512
        int t = (int)(i & 511) * 4;
        int len = seq_len[b];
        f32x4 pv = *(const f32x4*)&padded[i * 4];
        f32x4 yv = *(const f32x4*)&y[i * 4];
        #pragma unroll
        for (int e = 0; e < 4; ++e)
            if (t + e < len) { float d = pv[e] - yv[e]; s += d * d; cnt += 1.0f; }
    }
    for (int m = 1; m < 64; m <<= 1) { s += __shfl_xor(s, m); cnt += __shfl_xor(cnt, m); }
    if ((threadIdx.x & 63) == 0) { atomicAdd(&acc2[0], s); atomicAdd(&acc2[1], cnt); }
}

extern "C" __global__ void fin_kernel(const float* __restrict__ acc2, float* __restrict__ out)
{
    out[0] = acc2[0] / acc2[1];
}

// ---------------------------------------------------------------------------
extern "C" void kernel_launch(void* const* d_in, const int* in_sizes, int n_in,
                              void* d_out, int out_size, void* d_ws, size_t ws_size,
                              hipStream_t stream)
{
    const float* padded = (const float*)d_in[0];
    const int*   seq    = (const int*)  d_in[1];
    const float* eWih   = (const float*)d_in[2];
    const float* eWhh   = (const float*)d_in[3];
    const float* eb     = (const float*)d_in[4];
    const float* elW    = (const float*)d_in[5];
    const float* elb    = (const float*)d_in[6];
    const float* dlW    = (const float*)d_in[7];
    const float* dlb    = (const float*)d_in[8];
    const float* dWih   = (const float*)d_in[9];
    const float* dWhh   = (const float*)d_in[10];
    const float* db     = (const float*)d_in[11];
    const float* outW   = (const float*)d_in[12];
    const float* outb   = (const float*)d_in[13];
    float* out = (float*)d_out;

    float* ws    = (float*)d_ws;
    float* h_enc = ws;
    float* c_enc = ws + (long)B * H;
    float* hd    = ws + 2L * B * H;
    float* y0c   = ws + 3L * B * H;
    float* acc2  = ws + 3L * B * H + B;

    float* out_pad = out + 1;
    float* out_y   = out + 1 + (long)B * T;
    float* out_hz  = out + 1 + 2L * (long)B * T;

    hipMemcpyAsync(out_pad, padded, (long)B * T * sizeof(float),
                   hipMemcpyDeviceToDevice, stream);
    hipMemsetAsync(acc2, 0, 2 * sizeof(float), stream);

    enc_kernel<<<NB, NTHREADS, 0, stream>>>(padded, seq, eWih, eWhh, eb, h_enc, c_enc);
    mid_kernel<<<B / 256, 256, 0, stream>>>(h_enc, elW, elb, dlW, dlb, outW, outb,
                                            out_hz, hd, y0c);
    dec_kernel<<<NB, NTHREADS, 0, stream>>>(hd, c_enc, dWih, dWhh, db, outW, outb, y0c, out_y);
    loss_kernel<<<1024, 256, 0, stream>>>(padded, out_y, seq, acc2);
    fin_kernel<<<1, 1, 0, stream>>>(acc2, out);
}

// Round 11
// 1733.416 us; speedup vs baseline: 1.0473x; 1.0140x over previous
//
#include <hip/hip_runtime.h>

#define B 4096
#define T 2048
#define H 64
#define NBATCH 16
#define NB (B / NBATCH)     // 256 blocks -> 1 per CU
#define NTHREADS 512        // 8 waves -> 2 waves/SIMD, 2 cells/lane (dual-tile)

typedef __attribute__((ext_vector_type(8))) short short8;
typedef __attribute__((ext_vector_type(4))) float f32x4;
typedef __attribute__((ext_vector_type(2))) float f32x2;

__device__ __forceinline__ float ex2(float x) { return __builtin_amdgcn_exp2f(x); }
__device__ __forceinline__ unsigned short f2bf(float f) {  // RNE f32->bf16
    unsigned u = __builtin_bit_cast(unsigned, f);
    u += 0x7fffu + ((u >> 16) & 1u);
    return (unsigned short)(u >> 16);
}
// Pack two f32 -> two bf16 (RNE) in one instruction.
__device__ __forceinline__ unsigned pk_bf16(float a, float b) {
    unsigned r;
    asm("v_cvt_pk_bf16_f32 %0, %1, %2" : "=v"(r) : "v"(a), "v"(b));
    return r;
}
// Packed f32 (CDNA full-rate dual-FP32): 1 instr = 2 FLOPs/lane.
__device__ __forceinline__ f32x2 pk_mul(f32x2 a, f32x2 b) {
    f32x2 d; asm("v_pk_mul_f32 %0, %1, %2" : "=v"(d) : "v"(a), "v"(b)); return d;
}
__device__ __forceinline__ f32x2 pk_add(f32x2 a, f32x2 b) {
    f32x2 d; asm("v_pk_add_f32 %0, %1, %2" : "=v"(d) : "v"(a), "v"(b)); return d;
}
__device__ __forceinline__ f32x2 pk_fma(f32x2 a, f32x2 b, f32x2 c) {
    f32x2 d; asm("v_pk_fma_f32 %0, %1, %2, %3" : "=v"(d) : "v"(a), "v"(b), "v"(c)); return d;
}
__device__ __forceinline__ f32x2 pex2(f32x2 a) {   // elementwise 2^x
    float x, y;
    asm("v_exp_f32 %0, %1" : "=v"(x) : "v"(a.x));
    asm("v_exp_f32 %0, %1" : "=v"(y) : "v"(a.y));
    return (f32x2){x, y};
}
__device__ __forceinline__ f32x2 prcp(f32x2 a) {   // elementwise 1/x
    float x, y;
    asm("v_rcp_f32 %0, %1" : "=v"(x) : "v"(a.x));
    asm("v_rcp_f32 %0, %1" : "=v"(y) : "v"(a.y));
    return (f32x2){x, y};
}
__device__ __forceinline__ float med3(float x, float lo, float hi) {  // clamp, 1 instr
    float d; asm("v_med3_f32 %0, %1, %2, %3" : "=v"(d) : "v"(x), "v"(lo), "v"(hi));
    return d;
}
// LDS-only barrier: drain lgkm (ds ops) but leave global loads in flight.
__device__ __forceinline__ void lds_barrier() {
    asm volatile("s_waitcnt lgkmcnt(0)\n\ts_barrier" ::: "memory");
}

// Packed dual-cell LSTM update. Inputs are the gate-interleaved MFMA quads:
//   z0 = {i_A, i_B, f_A, f_B},  z1 = {g_A, g_B, o_A, o_B}
// Exact math, single rcp for c':
//   c' = [c*(1+p0)(1+v) + (1-v)(1+pf)] / [(1+pf)(1+p0)(1+v)]
//   h  = (1-r) / ((1+s)(1+r)),  p*=2^(-1.4427*gate), v,r=2^(-2.8854*{g,cc})
__device__ __forceinline__ void cellstep2(const f32x4 z0, const f32x4 z1,
                                          f32x2& csp, f32x2& hsp, bool act) {
    const f32x2 ke2  = {-1.4426950408889634f, -1.4426950408889634f};
    const f32x2 kt2  = {-2.8853900817779268f, -2.8853900817779268f};
    const f32x2 one2 = {1.0f, 1.0f};
    const f32x2 mone2= {-1.0f, -1.0f};
    f32x2 pi = {z0[0], z0[1]}, pf = {z0[2], z0[3]};
    f32x2 pg = {z1[0], z1[1]}, po = {z1[2], z1[3]};
    f32x2 ei = pex2(pk_mul(pi, ke2));        // e^{-i}
    f32x2 ef = pex2(pk_mul(pf, ke2));        // e^{-f}
    f32x2 eg = pex2(pk_mul(pg, kt2));        // e^{-2g}
    f32x2 eo = pex2(pk_mul(po, ke2));        // e^{-o}
    f32x2 t1 = pk_add(ei, one2);             // 1+p0
    f32x2 t3 = pk_add(ef, one2);             // 1+pf
    f32x2 t2 = pk_add(eg, one2);             // 1+v
    f32x2 u  = pk_fma(eg, mone2, one2);      // 1-v
    f32x2 m1 = pk_mul(t1, t2);
    f32x2 D  = pk_mul(m1, t3);
    f32x2 rD = prcp(D);
    f32x2 N  = pk_fma(csp, m1, pk_mul(u, t3));
    f32x2 cn = pk_mul(N, rD);                // c'
    float ccx = med3(cn.x, -15.f, 15.f);
    float ccy = med3(cn.y, -15.f, 15.f);
    f32x2 er = pex2(pk_mul((f32x2){ccx, ccy}, kt2));  // e^{-2cc}
    f32x2 t5 = pk_add(er, one2);             // 1+r
    f32x2 w1 = pk_fma(er, mone2, one2);      // 1-r
    f32x2 t4 = pk_add(eo, one2);             // 1+s
    f32x2 hn = pk_mul(w1, prcp(pk_mul(t4, t5)));
    if (act) { csp = cn; hsp = hn; }
}

// ---------------------------------------------------------------------------
// Encoder: 256 blocks x 512 threads (8 waves, 2/SIMD), 16 batches, 2 cells/lane.
// GATE-INTERLEAVED tiles (r8-verified): tile 0 C = {i_A,i_B,f_A,f_B}, tile 1 =
// {g_A,g_B,o_A,o_B} for adjacent units uA=w*8+2hi, uB=uA+1. Chained K-half
// MFMA accumulate (r9: chaining near-free; split-acc regressed). Scalar z-init
// (r10: pk_fma z-init put movs on the MFMA-input path; regressed).
// ---------------------------------------------------------------------------
extern "C" __global__ void __launch_bounds__(NTHREADS, 2)
enc_kernel(const float* __restrict__ padded, const int* __restrict__ seq_len,
           const float* __restrict__ Wih, const float* __restrict__ Whh,
           const float* __restrict__ bias,
           float* __restrict__ h_out, float* __restrict__ c_out)
{
    __shared__ unsigned short hX[2][NBATCH][72];
    __shared__ int slen[NBATCH];

    const int tid = threadIdx.x;
    const int w = tid >> 6, L = tid & 63, lo = L & 15, hi = L >> 4;
    const int b0 = blockIdx.x * NBATCH;
    const int unitA = w * 8 + 2 * hi;      // even unit; uB = unitA+1

    // A-frags, gate-interleaved rows G(m,rt)
    short8 af[2][2];
    #pragma unroll
    for (int rt = 0; rt < 2; ++rt) {
        const int G = (rt * 2 + ((lo >> 1) & 1)) * 64 + w * 8 + 2 * (lo >> 2) + (lo & 1);
        #pragma unroll
        for (int kk = 0; kk < 2; ++kk) {
            const float* src = Whh + (long)G * H + kk * 32 + hi * 8;
            short8 f;
            #pragma unroll
            for (int j = 0; j < 8; ++j) f[j] = (short)f2bf(src[j]);
            af[rt][kk] = f;
        }
    }
    // z-init coefs: quad elem r of tile rt = gate (rt*2+(r>>1)), unit unitA+(r&1)
    float b_g[2][4], wi_g[2][4];
    #pragma unroll
    for (int rt = 0; rt < 2; ++rt)
        #pragma unroll
        for (int r = 0; r < 4; ++r) {
            const int G2 = (rt * 2 + (r >> 1)) * 64 + unitA + (r & 1);
            b_g[rt][r] = bias[G2];
            wi_g[rt][r] = Wih[G2];
        }

    for (int idx = tid; idx < NBATCH * 64; idx += NTHREADS)
        hX[0][idx >> 6][idx & 63] = 0;
    if (tid < NBATCH) slen[tid] = seq_len[b0 + tid];
    lds_barrier();

    int maxlen = 1;
    #pragma unroll
    for (int i = 0; i < NBATCH; ++i) maxlen = max(maxlen, slen[i]);
    const int len_lo = slen[lo];

    const float* xrow = padded + (long)(b0 + lo) * T;
    f32x4 xc = *(const f32x4*)(xrow);
    f32x4 xn = *(const f32x4*)(xrow + 4);

    f32x2 csp = {0.f, 0.f}, hsp = {0.f, 0.f};

#define ESTEP(P, XI)                                                          \
    {                                                                         \
        const float x = xc[XI];                                               \
        short8 hb0 = *(const short8*)&hX[P][lo][hi * 8];                      \
        short8 hb1 = *(const short8*)&hX[P][lo][32 + hi * 8];                 \
        f32x4 z0 = {b_g[0][0] + wi_g[0][0] * x, b_g[0][1] + wi_g[0][1] * x,   \
                    b_g[0][2] + wi_g[0][2] * x, b_g[0][3] + wi_g[0][3] * x};  \
        f32x4 z1 = {b_g[1][0] + wi_g[1][0] * x, b_g[1][1] + wi_g[1][1] * x,   \
                    b_g[1][2] + wi_g[1][2] * x, b_g[1][3] + wi_g[1][3] * x};  \
        z0 = __builtin_amdgcn_mfma_f32_16x16x32_bf16(af[0][0], hb0, z0, 0,0,0); \
        z1 = __builtin_amdgcn_mfma_f32_16x16x32_bf16(af[1][0], hb0, z1, 0,0,0); \
        z0 = __builtin_amdgcn_mfma_f32_16x16x32_bf16(af[0][1], hb1, z0, 0,0,0); \
        z1 = __builtin_amdgcn_mfma_f32_16x16x32_bf16(af[1][1], hb1, z1, 0,0,0); \
        const bool act = (t + XI) < len_lo;                                   \
        cellstep2(z0, z1, csp, hsp, act);                                     \
        *(unsigned*)&hX[(P) ^ 1][lo][unitA] = pk_bf16(hsp.x, hsp.y);          \
        lds_barrier();                                                        \
    }

    for (int t = 0; t < maxlen; t += 4) {
        int nb = t + 8; if (nb > T - 4) nb = T - 4;
        f32x4 xf = *(const f32x4*)(xrow + nb);   // 8-step-ahead prefetch
        ESTEP(0, 0) ESTEP(1, 1) ESTEP(0, 2) ESTEP(1, 3)
        xc = xn; xn = xf;
    }
#undef ESTEP

    *(f32x2*)&h_out[(long)(b0 + lo) * H + unitA] = hsp;
    *(f32x2*)&c_out[(long)(b0 + lo) * H + unitA] = csp;
}

// ---------------------------------------------------------------------------
// Bottleneck + y0 correction term for the decoder's rank-1 fold.
// ---------------------------------------------------------------------------
extern "C" __global__ void __launch_bounds__(256)
mid_kernel(const float* __restrict__ h_enc,
           const float* __restrict__ eW, const float* __restrict__ eb,
           const float* __restrict__ dW, const float* __restrict__ db,
           const float* __restrict__ outW, const float* __restrict__ outb,
           float* __restrict__ hz_out, float* __restrict__ hd_out,
           float* __restrict__ y0c)
{
    int b = blockIdx.x * blockDim.x + threadIdx.x;
    if (b >= B) return;
    const float* h = h_enc + (long)b * H;
    float hz[3];
    #pragma unroll
    for (int j = 0; j < 3; ++j) {
        float s = eb[j];
        for (int k = 0; k < H; ++k) s += h[k] * eW[j*H + k];
        hz[j] = 1.0f / (1.0f + __builtin_expf(-s));
        hz_out[b*3 + j] = hz[j];
    }
    float y0 = outb[0];
    for (int u = 0; u < H; ++u) {
        float hd = db[u] + hz[0]*dW[u*3] + hz[1]*dW[u*3+1] + hz[2]*dW[u*3+2];
        hd_out[(long)b*H + u] = hd;
        y0 += outW[u] * hd;
    }
    y0c[b] = y0;
}

// ---------------------------------------------------------------------------
// Decoder: rank-1 fold (W' = Whh + Wih (x) outW, b' = b + Wih*outb) -> pure
// LSTM. Same structure + gate-interleaved packed act. y_{t-1} via 2 extra
// MFMAs rotating across waves (w==t&7), one step delayed. t=0 corr peeled.
// ---------------------------------------------------------------------------
extern "C" __global__ void __launch_bounds__(NTHREADS, 2)
dec_kernel(const float* __restrict__ hd, const float* __restrict__ c_in,
           const float* __restrict__ Wih, const float* __restrict__ Whh,
           const float* __restrict__ bias, const float* __restrict__ outW,
           const float* __restrict__ outb, const float* __restrict__ y0c,
           float* __restrict__ y_out)
{
    __shared__ unsigned short hX[2][NBATCH][72];

    const int tid = threadIdx.x;
    const int w = tid >> 6, L = tid & 63, lo = L & 15, hi = L >> 4;
    const int b0 = blockIdx.x * NBATCH;
    const int unitA = w * 8 + 2 * hi;

    short8 af[2][2];
    #pragma unroll
    for (int rt = 0; rt < 2; ++rt) {
        const int G = (rt * 2 + ((lo >> 1) & 1)) * 64 + w * 8 + 2 * (lo >> 2) + (lo & 1);
        const float wir = Wih[G];
        #pragma unroll
        for (int kk = 0; kk < 2; ++kk) {
            const float* src = Whh + (long)G * H + kk * 32 + hi * 8;
            const float* ow  = outW + kk * 32 + hi * 8;
            short8 f;
            #pragma unroll
            for (int j = 0; j < 8; ++j) f[j] = (short)f2bf(src[j] + wir * ow[j]);
            af[rt][kk] = f;
        }
    }
    const float outb_s = outb[0];
    const float y0 = y0c[b0 + lo];
    float zb[2][4], corr[2][4];
    #pragma unroll
    for (int rt = 0; rt < 2; ++rt)
        #pragma unroll
        for (int r = 0; r < 4; ++r) {
            const int G2 = (rt * 2 + (r >> 1)) * 64 + unitA + (r & 1);
            zb[rt][r] = bias[G2] + Wih[G2] * outb_s;
            corr[rt][r] = Wih[G2] * y0;
        }

    short8 ya[2];   // y-extraction A-frag: row 0 = outW, rows 1..15 = 0
    #pragma unroll
    for (int kk = 0; kk < 2; ++kk) {
        short8 f = (short8)0;
        if (lo == 0)
            #pragma unroll
            for (int j = 0; j < 8; ++j) f[j] = (short)f2bf(outW[kk*32 + hi*8 + j]);
        ya[kk] = f;
    }

    for (int idx = tid; idx < NBATCH * 64; idx += NTHREADS)
        hX[0][idx >> 6][idx & 63] = f2bf(hd[(long)(b0 + (idx >> 6)) * H + (idx & 63)]);
    f32x2 csp = *(const f32x2*)&c_in[(long)(b0 + lo) * H + unitA];
    f32x2 hsp = {0.f, 0.f};
    lds_barrier();

#define DSTEP(P, CORR, TT)                                                    \
    {                                                                         \
        short8 hb0 = *(const short8*)&hX[P][lo][hi * 8];                      \
        short8 hb1 = *(const short8*)&hX[P][lo][32 + hi * 8];                 \
        f32x4 z0 = {zb[0][0], zb[0][1], zb[0][2], zb[0][3]};                  \
        f32x4 z1 = {zb[1][0], zb[1][1], zb[1][2], zb[1][3]};                  \
        z0 = __builtin_amdgcn_mfma_f32_16x16x32_bf16(af[0][0], hb0, z0, 0,0,0); \
        z1 = __builtin_amdgcn_mfma_f32_16x16x32_bf16(af[1][0], hb0, z1, 0,0,0); \
        z0 = __builtin_amdgcn_mfma_f32_16x16x32_bf16(af[0][1], hb1, z0, 0,0,0); \
        z1 = __builtin_amdgcn_mfma_f32_16x16x32_bf16(af[1][1], hb1, z1, 0,0,0); \
        if (w == ((TT) & 7)) {  /* y_{t-1} = outW.h_{t-1}+outb, rotated */    \
            f32x4 zy = {outb_s, outb_s, outb_s, outb_s};                      \
            zy = __builtin_amdgcn_mfma_f32_16x16x32_bf16(ya[0], hb0, zy, 0,0,0); \
            zy = __builtin_amdgcn_mfma_f32_16x16x32_bf16(ya[1], hb1, zy, 0,0,0); \
            if ((TT) > 0 && hi == 0)                                          \
                y_out[(long)(b0 + lo) * T + ((TT) - 1)] = zy[0];              \
        }                                                                     \
        if (CORR) {                                                           \
            _Pragma("unroll")                                                 \
            for (int r = 0; r < 4; ++r) { z0[r] -= corr[0][r]; z1[r] -= corr[1][r]; } \
        }                                                                     \
        cellstep2(z0, z1, csp, hsp, true);                                    \
        *(unsigned*)&hX[(P) ^ 1][lo][unitA] = pk_bf16(hsp.x, hsp.y);          \
        lds_barrier();                                                        \
    }

    DSTEP(0, 1, 0) DSTEP(1, 0, 1) DSTEP(0, 0, 2) DSTEP(1, 0, 3)
    for (int t = 4; t < T; t += 4) {
        DSTEP(0, 0, t) DSTEP(1, 0, t + 1) DSTEP(0, 0, t + 2) DSTEP(1, 0, t + 3)
    }
#undef DSTEP

    if (w == 0) {       // final y_{T-1} (T even -> parity 0)
        short8 hb0 = *(const short8*)&hX[0][lo][hi * 8];
        short8 hb1 = *(const short8*)&hX[0][lo][32 + hi * 8];
        f32x4 zy = {outb_s, outb_s, outb_s, outb_s};
        zy = __builtin_amdgcn_mfma_f32_16x16x32_bf16(ya[0], hb0, zy, 0,0,0);
        zy = __builtin_amdgcn_mfma_f32_16x16x32_bf16(ya[1], hb1, zy, 0,0,0);
        if (hi == 0) y_out[(long)(b0 + lo) * T + (T - 1)] = zy[0];
    }
}

// ---------------------------------------------------------------------------
extern "C" __global__ void __launch_bounds__(256)
loss_kernel(const float* __restrict__ padded, const float* __restrict__ y,
            const int* __restrict__ seq_len, float* __restrict__ acc2)
{
    const long n4 = (long)B * T / 4;
    long i0 = (long)(blockIdx.x * blockDim.x + threadIdx.x);
    long stride = (long)gridDim.x * blockDim.x;
    float s = 0.f, cnt = 0.f;
    for (long i = i0; i < n4; i += stride) {
        int b = (int)(i >> 9);                  // T/4 = 512
        int t = (int)(i & 511) * 4;
        int len = seq_len[b];
        f32x4 pv = *(const f32x4*)&padded[i * 4];
        f32x4 yv = *(const f32x4*)&y[i * 4];
        #pragma unroll
        for (int e = 0; e < 4; ++e)
            if (t + e < len) { float d = pv[e] - yv[e]; s += d * d; cnt += 1.0f; }
    }
    for (int m = 1; m < 64; m <<= 1) { s += __shfl_xor(s, m); cnt += __shfl_xor(cnt, m); }
    if ((threadIdx.x & 63) == 0) { atomicAdd(&acc2[0], s); atomicAdd(&acc2[1], cnt); }
}

extern "C" __global__ void fin_kernel(const float* __restrict__ acc2, float* __restrict__ out)
{
    out[0] = acc2[0] / acc2[1];
}

// ---------------------------------------------------------------------------
extern "C" void kernel_launch(void* const* d_in, const int* in_sizes, int n_in,
                              void* d_out, int out_size, void* d_ws, size_t ws_size,
                              hipStream_t stream)
{
    const float* padded = (const float*)d_in[0];
    const int*   seq    = (const int*)  d_in[1];
    const float* eWih   = (const float*)d_in[2];
    const float* eWhh   = (const float*)d_in[3];
    const float* eb     = (const float*)d_in[4];
    const float* elW    = (const float*)d_in[5];
    const float* elb    = (const float*)d_in[6];
    const float* dlW    = (const float*)d_in[7];
    const float* dlb    = (const float*)d_in[8];
    const float* dWih   = (const float*)d_in[9];
    const float* dWhh   = (const float*)d_in[10];
    const float* db     = (const float*)d_in[11];
    const float* outW   = (const float*)d_in[12];
    const float* outb   = (const float*)d_in[13];
    float* out = (float*)d_out;

    float* ws    = (float*)d_ws;
    float* h_enc = ws;
    float* c_enc = ws + (long)B * H;
    float* hd    = ws + 2L * B * H;
    float* y0c   = ws + 3L * B * H;
    float* acc2  = ws + 3L * B * H + B;

    float* out_pad = out + 1;
    float* out_y   = out + 1 + (long)B * T;
    float* out_hz  = out + 1 + 2L * (long)B * T;

    hipMemcpyAsync(out_pad, padded, (long)B * T * sizeof(float),
                   hipMemcpyDeviceToDevice, stream);
    hipMemsetAsync(acc2, 0, 2 * sizeof(float), stream);

    enc_kernel<<<NB, NTHREADS, 0, stream>>>(padded, seq, eWih, eWhh, eb, h_enc, c_enc);
    mid_kernel<<<B / 256, 256, 0, stream>>>(h_enc, elW, elb, dlW, dlb, outW, outb,
                                            out_hz, hd, y0c);
    dec_kernel<<<NB, NTHREADS, 0, stream>>>(hd, c_enc, dWih, dWhh, db, outW, outb, y0c, out_y);
    loss_kernel<<<1024, 256, 0, stream>>>(padded, out_y, seq, acc2);
    fin_kernel<<<1, 1, 0, stream>>>(acc2, out);
}

// Round 12
// 1713.961 us; speedup vs baseline: 1.0592x; 1.0114x over previous
//
#include <hip/hip_runtime.h>

#define B 4096
#define T 2048
#define H 64
#define NBATCH 16
#define NB (B / NBATCH)     // 256 blocks -> 1 per CU
#define NTHREADS 512        // 8 waves -> 2 waves/SIMD, 2 cells/lane (dual-tile)

typedef __attribute__((ext_vector_type(8))) short short8;
typedef __attribute__((ext_vector_type(4))) float f32x4;
typedef __attribute__((ext_vector_type(2))) float f32x2;

__device__ __forceinline__ float ex2(float x) { return __builtin_amdgcn_exp2f(x); }
__device__ __forceinline__ unsigned short f2bf(float f) {  // RNE f32->bf16
    unsigned u = __builtin_bit_cast(unsigned, f);
    u += 0x7fffu + ((u >> 16) & 1u);
    return (unsigned short)(u >> 16);
}
// Pack two f32 -> two bf16 (RNE) in one instruction.
__device__ __forceinline__ unsigned pk_bf16(float a, float b) {
    unsigned r;
    asm("v_cvt_pk_bf16_f32 %0, %1, %2" : "=v"(r) : "v"(a), "v"(b));
    return r;
}
// Packed f32 (CDNA full-rate dual-FP32): 1 instr = 2 FLOPs/lane.
__device__ __forceinline__ f32x2 pk_mul(f32x2 a, f32x2 b) {
    f32x2 d; asm("v_pk_mul_f32 %0, %1, %2" : "=v"(d) : "v"(a), "v"(b)); return d;
}
__device__ __forceinline__ f32x2 pk_add(f32x2 a, f32x2 b) {
    f32x2 d; asm("v_pk_add_f32 %0, %1, %2" : "=v"(d) : "v"(a), "v"(b)); return d;
}
__device__ __forceinline__ f32x2 pk_fma(f32x2 a, f32x2 b, f32x2 c) {
    f32x2 d; asm("v_pk_fma_f32 %0, %1, %2, %3" : "=v"(d) : "v"(a), "v"(b), "v"(c)); return d;
}
__device__ __forceinline__ f32x2 pex2(f32x2 a) {   // elementwise 2^x
    float x, y;
    asm("v_exp_f32 %0, %1" : "=v"(x) : "v"(a.x));
    asm("v_exp_f32 %0, %1" : "=v"(y) : "v"(a.y));
    return (f32x2){x, y};
}
__device__ __forceinline__ f32x2 prcp(f32x2 a) {   // elementwise 1/x
    float x, y;
    asm("v_rcp_f32 %0, %1" : "=v"(x) : "v"(a.x));
    asm("v_rcp_f32 %0, %1" : "=v"(y) : "v"(a.y));
    return (f32x2){x, y};
}
__device__ __forceinline__ float med3(float x, float lo, float hi) {  // clamp, 1 instr
    float d; asm("v_med3_f32 %0, %1, %2, %3" : "=v"(d) : "v"(x), "v"(lo), "v"(hi));
    return d;
}
// LDS-only barrier: drain lgkm (ds ops) but leave global loads in flight.
__device__ __forceinline__ void lds_barrier() {
    asm volatile("s_waitcnt lgkmcnt(0)\n\ts_barrier" ::: "memory");
}

// Packed dual-cell LSTM update. Inputs are the gate-interleaved MFMA quads:
//   z0 = {i_A, i_B, f_A, f_B},  z1 = {g_A, g_B, o_A, o_B}
// Exact math, single rcp for c':
//   c' = [c*(1+p0)(1+v) + (1-v)(1+pf)] / [(1+pf)(1+p0)(1+v)]
//   h  = (1-r) / ((1+s)(1+r)),  p*=2^(-1.4427*gate), v,r=2^(-2.8854*{g,cc})
__device__ __forceinline__ void cellstep2(const f32x4 z0, const f32x4 z1,
                                          f32x2& csp, f32x2& hsp, bool act) {
    const f32x2 ke2  = {-1.4426950408889634f, -1.4426950408889634f};
    const f32x2 kt2  = {-2.8853900817779268f, -2.8853900817779268f};
    const f32x2 one2 = {1.0f, 1.0f};
    const f32x2 mone2= {-1.0f, -1.0f};
    f32x2 pi = {z0[0], z0[1]}, pf = {z0[2], z0[3]};
    f32x2 pg = {z1[0], z1[1]}, po = {z1[2], z1[3]};
    f32x2 ei = pex2(pk_mul(pi, ke2));        // e^{-i}
    f32x2 ef = pex2(pk_mul(pf, ke2));        // e^{-f}
    f32x2 eg = pex2(pk_mul(pg, kt2));        // e^{-2g}
    f32x2 eo = pex2(pk_mul(po, ke2));        // e^{-o}
    f32x2 t1 = pk_add(ei, one2);             // 1+p0
    f32x2 t3 = pk_add(ef, one2);             // 1+pf
    f32x2 t2 = pk_add(eg, one2);             // 1+v
    f32x2 u  = pk_fma(eg, mone2, one2);      // 1-v
    f32x2 m1 = pk_mul(t1, t2);
    f32x2 D  = pk_mul(m1, t3);
    f32x2 rD = prcp(D);
    f32x2 N  = pk_fma(csp, m1, pk_mul(u, t3));
    f32x2 cn = pk_mul(N, rD);                // c'
    float ccx = med3(cn.x, -15.f, 15.f);
    float ccy = med3(cn.y, -15.f, 15.f);
    f32x2 er = pex2(pk_mul((f32x2){ccx, ccy}, kt2));  // e^{-2cc}
    f32x2 t5 = pk_add(er, one2);             // 1+r
    f32x2 w1 = pk_fma(er, mone2, one2);      // 1-r
    f32x2 t4 = pk_add(eo, one2);             // 1+s
    f32x2 hn = pk_mul(w1, prcp(pk_mul(t4, t5)));
    if (act) { csp = cn; hsp = hn; }
}

// ---------------------------------------------------------------------------
// Encoder: 256 blocks x 512 threads (8 waves, 2/SIMD), 16 batches, 2 cells/lane.
// GATE-INTERLEAVED tiles (r8-verified): tile 0 C = {i_A,i_B,f_A,f_B}, tile 1 =
// {g_A,g_B,o_A,o_B} for adjacent units uA=w*8+2hi, uB=uA+1. Chained K-half
// MFMA accumulate (r9: chaining near-free; split-acc regressed). Scalar z-init
// (r10: pk_fma z-init put movs on the MFMA-input path; regressed).
// ---------------------------------------------------------------------------
extern "C" __global__ void __launch_bounds__(NTHREADS, 2)
enc_kernel(const float* __restrict__ padded, const int* __restrict__ seq_len,
           const float* __restrict__ Wih, const float* __restrict__ Whh,
           const float* __restrict__ bias,
           float* __restrict__ h_out, float* __restrict__ c_out)
{
    __shared__ unsigned short hX[2][NBATCH][72];
    __shared__ int slen[NBATCH];

    const int tid = threadIdx.x;
    const int w = tid >> 6, L = tid & 63, lo = L & 15, hi = L >> 4;
    const int b0 = blockIdx.x * NBATCH;
    const int unitA = w * 8 + 2 * hi;      // even unit; uB = unitA+1

    // A-frags, gate-interleaved rows G(m,rt)
    short8 af[2][2];
    #pragma unroll
    for (int rt = 0; rt < 2; ++rt) {
        const int G = (rt * 2 + ((lo >> 1) & 1)) * 64 + w * 8 + 2 * (lo >> 2) + (lo & 1);
        #pragma unroll
        for (int kk = 0; kk < 2; ++kk) {
            const float* src = Whh + (long)G * H + kk * 32 + hi * 8;
            short8 f;
            #pragma unroll
            for (int j = 0; j < 8; ++j) f[j] = (short)f2bf(src[j]);
            af[rt][kk] = f;
        }
    }
    // z-init coefs: quad elem r of tile rt = gate (rt*2+(r>>1)), unit unitA+(r&1)
    float b_g[2][4], wi_g[2][4];
    #pragma unroll
    for (int rt = 0; rt < 2; ++rt)
        #pragma unroll
        for (int r = 0; r < 4; ++r) {
            const int G2 = (rt * 2 + (r >> 1)) * 64 + unitA + (r & 1);
            b_g[rt][r] = bias[G2];
            wi_g[rt][r] = Wih[G2];
        }

    for (int idx = tid; idx < NBATCH * 64; idx += NTHREADS)
        hX[0][idx >> 6][idx & 63] = 0;
    if (tid < NBATCH) slen[tid] = seq_len[b0 + tid];
    lds_barrier();

    int maxlen = 1;
    #pragma unroll
    for (int i = 0; i < NBATCH; ++i) maxlen = max(maxlen, slen[i]);
    const int len_lo = slen[lo];

    const float* xrow = padded + (long)(b0 + lo) * T;
    f32x4 xc = *(const f32x4*)(xrow);
    f32x4 xn = *(const f32x4*)(xrow + 4);

    f32x2 csp = {0.f, 0.f}, hsp = {0.f, 0.f};

#define ESTEP(P, XI)                                                          \
    {                                                                         \
        const float x = xc[XI];                                               \
        short8 hb0 = *(const short8*)&hX[P][lo][hi * 8];                      \
        short8 hb1 = *(const short8*)&hX[P][lo][32 + hi * 8];                 \
        f32x4 z0 = {b_g[0][0] + wi_g[0][0] * x, b_g[0][1] + wi_g[0][1] * x,   \
                    b_g[0][2] + wi_g[0][2] * x, b_g[0][3] + wi_g[0][3] * x};  \
        f32x4 z1 = {b_g[1][0] + wi_g[1][0] * x, b_g[1][1] + wi_g[1][1] * x,   \
                    b_g[1][2] + wi_g[1][2] * x, b_g[1][3] + wi_g[1][3] * x};  \
        z0 = __builtin_amdgcn_mfma_f32_16x16x32_bf16(af[0][0], hb0, z0, 0,0,0); \
        z1 = __builtin_amdgcn_mfma_f32_16x16x32_bf16(af[1][0], hb0, z1, 0,0,0); \
        z0 = __builtin_amdgcn_mfma_f32_16x16x32_bf16(af[0][1], hb1, z0, 0,0,0); \
        z1 = __builtin_amdgcn_mfma_f32_16x16x32_bf16(af[1][1], hb1, z1, 0,0,0); \
        const bool act = (t + XI) < len_lo;                                   \
        cellstep2(z0, z1, csp, hsp, act);                                     \
        *(unsigned*)&hX[(P) ^ 1][lo][unitA] = pk_bf16(hsp.x, hsp.y);          \
        lds_barrier();                                                        \
    }

    for (int t = 0; t < maxlen; t += 4) {
        int nb = t + 8; if (nb > T - 4) nb = T - 4;
        f32x4 xf = *(const f32x4*)(xrow + nb);   // 8-step-ahead prefetch
        ESTEP(0, 0) ESTEP(1, 1) ESTEP(0, 2) ESTEP(1, 3)
        xc = xn; xn = xf;
    }
#undef ESTEP

    *(f32x2*)&h_out[(long)(b0 + lo) * H + unitA] = hsp;
    *(f32x2*)&c_out[(long)(b0 + lo) * H + unitA] = csp;
}

// ---------------------------------------------------------------------------
// Bottleneck + y0 correction term for the decoder's rank-1 fold.
// ---------------------------------------------------------------------------
extern "C" __global__ void __launch_bounds__(256)
mid_kernel(const float* __restrict__ h_enc,
           const float* __restrict__ eW, const float* __restrict__ eb,
           const float* __restrict__ dW, const float* __restrict__ db,
           const float* __restrict__ outW, const float* __restrict__ outb,
           float* __restrict__ hz_out, float* __restrict__ hd_out,
           float* __restrict__ y0c)
{
    int b = blockIdx.x * blockDim.x + threadIdx.x;
    if (b >= B) return;
    const float* h = h_enc + (long)b * H;
    float hz[3];
    #pragma unroll
    for (int j = 0; j < 3; ++j) {
        float s = eb[j];
        for (int k = 0; k < H; ++k) s += h[k] * eW[j*H + k];
        hz[j] = 1.0f / (1.0f + __builtin_expf(-s));
        hz_out[b*3 + j] = hz[j];
    }
    float y0 = outb[0];
    for (int u = 0; u < H; ++u) {
        float hd = db[u] + hz[0]*dW[u*3] + hz[1]*dW[u*3+1] + hz[2]*dW[u*3+2];
        hd_out[(long)b*H + u] = hd;
        y0 += outW[u] * hd;
    }
    y0c[b] = y0;
}

// ---------------------------------------------------------------------------
// Decoder: rank-1 fold (W' = Whh + Wih (x) outW, b' = b + Wih*outb) -> pure
// LSTM. Same structure + gate-interleaved packed act. y_{t-1} via 2 extra
// MFMAs rotating across waves (w==t&7), one step delayed. t=0 corr peeled.
// ---------------------------------------------------------------------------
extern "C" __global__ void __launch_bounds__(NTHREADS, 2)
dec_kernel(const float* __restrict__ hd, const float* __restrict__ c_in,
           const float* __restrict__ Wih, const float* __restrict__ Whh,
           const float* __restrict__ bias, const float* __restrict__ outW,
           const float* __restrict__ outb, const float* __restrict__ y0c,
           float* __restrict__ y_out)
{
    __shared__ unsigned short hX[2][NBATCH][72];

    const int tid = threadIdx.x;
    const int w = tid >> 6, L = tid & 63, lo = L & 15, hi = L >> 4;
    const int b0 = blockIdx.x * NBATCH;
    const int unitA = w * 8 + 2 * hi;

    short8 af[2][2];
    #pragma unroll
    for (int rt = 0; rt < 2; ++rt) {
        const int G = (rt * 2 + ((lo >> 1) & 1)) * 64 + w * 8 + 2 * (lo >> 2) + (lo & 1);
        const float wir = Wih[G];
        #pragma unroll
        for (int kk = 0; kk < 2; ++kk) {
            const float* src = Whh + (long)G * H + kk * 32 + hi * 8;
            const float* ow  = outW + kk * 32 + hi * 8;
            short8 f;
            #pragma unroll
            for (int j = 0; j < 8; ++j) f[j] = (short)f2bf(src[j] + wir * ow[j]);
            af[rt][kk] = f;
        }
    }
    const float outb_s = outb[0];
    const float y0 = y0c[b0 + lo];
    float zb[2][4], corr[2][4];
    #pragma unroll
    for (int rt = 0; rt < 2; ++rt)
        #pragma unroll
        for (int r = 0; r < 4; ++r) {
            const int G2 = (rt * 2 + (r >> 1)) * 64 + unitA + (r & 1);
            zb[rt][r] = bias[G2] + Wih[G2] * outb_s;
            corr[rt][r] = Wih[G2] * y0;
        }

    short8 ya[2];   // y-extraction A-frag: row 0 = outW, rows 1..15 = 0
    #pragma unroll
    for (int kk = 0; kk < 2; ++kk) {
        short8 f = (short8)0;
        if (lo == 0)
            #pragma unroll
            for (int j = 0; j < 8; ++j) f[j] = (short)f2bf(outW[kk*32 + hi*8 + j]);
        ya[kk] = f;
    }

    for (int idx = tid; idx < NBATCH * 64; idx += NTHREADS)
        hX[0][idx >> 6][idx & 63] = f2bf(hd[(long)(b0 + (idx >> 6)) * H + (idx & 63)]);
    f32x2 csp = *(const f32x2*)&c_in[(long)(b0 + lo) * H + unitA];
    f32x2 hsp = {0.f, 0.f};
    lds_barrier();

#define DSTEP(P, CORR, TT)                                                    \
    {                                                                         \
        short8 hb0 = *(const short8*)&hX[P][lo][hi * 8];                      \
        short8 hb1 = *(const short8*)&hX[P][lo][32 + hi * 8];                 \
        f32x4 z0 = {zb[0][0], zb[0][1], zb[0][2], zb[0][3]};                  \
        f32x4 z1 = {zb[1][0], zb[1][1], zb[1][2], zb[1][3]};                  \
        z0 = __builtin_amdgcn_mfma_f32_16x16x32_bf16(af[0][0], hb0, z0, 0,0,0); \
        z1 = __builtin_amdgcn_mfma_f32_16x16x32_bf16(af[1][0], hb0, z1, 0,0,0); \
        z0 = __builtin_amdgcn_mfma_f32_16x16x32_bf16(af[0][1], hb1, z0, 0,0,0); \
        z1 = __builtin_amdgcn_mfma_f32_16x16x32_bf16(af[1][1], hb1, z1, 0,0,0); \
        if (w == ((TT) & 7)) {  /* y_{t-1} = outW.h_{t-1}+outb, rotated */    \
            f32x4 zy = {outb_s, outb_s, outb_s, outb_s};                      \
            zy = __builtin_amdgcn_mfma_f32_16x16x32_bf16(ya[0], hb0, zy, 0,0,0); \
            zy = __builtin_amdgcn_mfma_f32_16x16x32_bf16(ya[1], hb1, zy, 0,0,0); \
            if ((TT) > 0 && hi == 0)                                          \
                y_out[(long)(b0 + lo) * T + ((TT) - 1)] = zy[0];              \
        }                                                                     \
        if (CORR) {                                                           \
            _Pragma("unroll")                                                 \
            for (int r = 0; r < 4; ++r) { z0[r] -= corr[0][r]; z1[r] -= corr[1][r]; } \
        }                                                                     \
        cellstep2(z0, z1, csp, hsp, true);                                    \
        *(unsigned*)&hX[(P) ^ 1][lo][unitA] = pk_bf16(hsp.x, hsp.y);          \
        lds_barrier();                                                        \
    }

    DSTEP(0, 1, 0) DSTEP(1, 0, 1) DSTEP(0, 0, 2) DSTEP(1, 0, 3)
    for (int t = 4; t < T; t += 4) {
        DSTEP(0, 0, t) DSTEP(1, 0, t + 1) DSTEP(0, 0, t + 2) DSTEP(1, 0, t + 3)
    }
#undef DSTEP

    if (w == 0) {       // final y_{T-1} (T even -> parity 0)
        short8 hb0 = *(const short8*)&hX[0][lo][hi * 8];
        short8 hb1 = *(const short8*)&hX[0][lo][32 + hi * 8];
        f32x4 zy = {outb_s, outb_s, outb_s, outb_s};
        zy = __builtin_amdgcn_mfma_f32_16x16x32_bf16(ya[0], hb0, zy, 0,0,0);
        zy = __builtin_amdgcn_mfma_f32_16x16x32_bf16(ya[1], hb1, zy, 0,0,0);
        if (hi == 0) y_out[(long)(b0 + lo) * T + (T - 1)] = zy[0];
    }
}

// ---------------------------------------------------------------------------
// Loss + padded-copy fused: this kernel already streams every element of
// padded, so the out_pad copy rides along for free (saves the standalone
// 32MB memcpy pass + one dispatch). cnt via closed form clamp(len-t,0,4);
// s is bit-identical (masked elements contribute d=0).
// ---------------------------------------------------------------------------
extern "C" __global__ void __launch_bounds__(256)
loss_kernel(const float* __restrict__ padded, const float* __restrict__ y,
            const int* __restrict__ seq_len, float* __restrict__ acc2,
            float* __restrict__ out_pad)
{
    const long n4 = (long)B * T / 4;
    long i0 = (long)(blockIdx.x * blockDim.x + threadIdx.x);
    long stride = (long)gridDim.x * blockDim.x;
    float s = 0.f, cnt = 0.f;
    for (long i = i0; i < n4; i += stride) {
        int b = (int)(i >> 9);                  // T/4 = 512
        int t = (int)(i & 511) * 4;
        int len = seq_len[b];
        f32x4 pv = *(const f32x4*)&padded[i * 4];
        f32x4 yv = *(const f32x4*)&y[i * 4];
        *(f32x4*)&out_pad[i * 4] = pv;          // fused copy (bit-exact)
        cnt += (float)min(max(len - t, 0), 4);
        #pragma unroll
        for (int e = 0; e < 4; ++e) {
            float d = (t + e < len) ? (pv[e] - yv[e]) : 0.0f;
            s += d * d;
        }
    }
    for (int m = 1; m < 64; m <<= 1) { s += __shfl_xor(s, m); cnt += __shfl_xor(cnt, m); }
    if ((threadIdx.x & 63) == 0) { atomicAdd(&acc2[0], s); atomicAdd(&acc2[1], cnt); }
}

extern "C" __global__ void fin_kernel(const float* __restrict__ acc2, float* __restrict__ out)
{
    out[0] = acc2[0] / acc2[1];
}

// ---------------------------------------------------------------------------
extern "C" void kernel_launch(void* const* d_in, const int* in_sizes, int n_in,
                              void* d_out, int out_size, void* d_ws, size_t ws_size,
                              hipStream_t stream)
{
    const float* padded = (const float*)d_in[0];
    const int*   seq    = (const int*)  d_in[1];
    const float* eWih   = (const float*)d_in[2];
    const float* eWhh   = (const float*)d_in[3];
    const float* eb     = (const float*)d_in[4];
    const float* elW    = (const float*)d_in[5];
    const float* elb    = (const float*)d_in[6];
    const float* dlW    = (const float*)d_in[7];
    const float* dlb    = (const float*)d_in[8];
    const float* dWih   = (const float*)d_in[9];
    const float* dWhh   = (const float*)d_in[10];
    const float* db     = (const float*)d_in[11];
    const float* outW   = (const float*)d_in[12];
    const float* outb   = (const float*)d_in[13];
    float* out = (float*)d_out;

    float* ws    = (float*)d_ws;
    float* h_enc = ws;
    float* c_enc = ws + (long)B * H;
    float* hd    = ws + 2L * B * H;
    float* y0c   = ws + 3L * B * H;
    float* acc2  = ws + 3L * B * H + B;

    float* out_pad = out + 1;
    float* out_y   = out + 1 + (long)B * T;
    float* out_hz  = out + 1 + 2L * (long)B * T;

    hipMemsetAsync(acc2, 0, 2 * sizeof(float), stream);

    enc_kernel<<<NB, NTHREADS, 0, stream>>>(padded, seq, eWih, eWhh, eb, h_enc, c_enc);
    mid_kernel<<<B / 256, 256, 0, stream>>>(h_enc, elW, elb, dlW, dlb, outW, outb,
                                            out_hz, hd, y0c);
    dec_kernel<<<NB, NTHREADS, 0, stream>>>(hd, c_enc, dWih, dWhh, db, outW, outb, y0c, out_y);
    loss_kernel<<<1024, 256, 0, stream>>>(padded, out_y, seq, acc2, out_pad);
    fin_kernel<<<1, 1, 0, stream>>>(acc2, out);
}